// Round 1
// baseline (432.796 us; speedup 1.0000x reference)
//
#include <hip/hip_runtime.h>
#include <hip/hip_bf16.h>

typedef __bf16  bf8_t  __attribute__((ext_vector_type(8)));
typedef float   f4_t   __attribute__((ext_vector_type(4)));
typedef unsigned int u32;
typedef u32     u4_t   __attribute__((ext_vector_type(4)));

#define NB 32768

__device__ __forceinline__ float sigf(float x)   { return 1.0f / (1.0f + __expf(-x)); }
__device__ __forceinline__ float tanhf_(float x) { return 2.0f / (1.0f + __expf(-2.0f * x)) - 1.0f; }

#define MFMA16(a, b, c) __builtin_amdgcn_mfma_f32_16x16x32_bf16((a), (b), (c), 0, 0, 0)

// ---------------- prep: bf16 weight repacks ----------------
__global__ __launch_bounds__(256) void k_prep(
    const float* __restrict__ Wih, const float* __restrict__ Whh,
    const float* __restrict__ bih, const float* __restrict__ bhh,
    __bf16* __restrict__ Wcat, __bf16* __restrict__ Wsum, float* __restrict__ bsum)
{
  int tid = blockIdx.x * 256 + threadIdx.x;
  for (int i = tid; i < 256 * 128; i += 64 * 256) {
    int n = i >> 7, k = i & 127;
    float v = (k < 64) ? Wih[n * 64 + k] : Whh[n * 64 + (k - 64)];
    Wcat[i] = (__bf16)v;
  }
  { // tid < 16384 always (grid = 64*256)
    int n = tid >> 6, k = tid & 63;
    Wsum[tid] = (__bf16)(Wih[n * 64 + k] + Whh[n * 64 + k]);
  }
  if (tid < 256) bsum[tid] = bih[tid] + bhh[tid];
}

// ---------------- BN layer-1 batch stats ----------------
__global__ __launch_bounds__(256) void k_stats1(
    const float* __restrict__ x, const float* __restrict__ W1, float* __restrict__ stats)
{
  __shared__ float w1t[64 * 32];
  __shared__ float hbuf[256 * 36];
  int tid = threadIdx.x;
  int t = blockIdx.x >> 7, chunk = blockIdx.x & 127;
  int row = chunk * 256 + tid;
  #pragma unroll
  for (int i = 0; i < 8; ++i) { int e = tid * 8 + i; w1t[(e & 63) * 32 + (e >> 6)] = W1[e]; }
  __syncthreads();
  f4_t acc[8];
  #pragma unroll
  for (int jq = 0; jq < 8; ++jq) acc[jq] = (f4_t){0.f, 0.f, 0.f, 0.f};
  const f4_t* xrow = (const f4_t*)(x + ((size_t)t * NB + row) * 64);
  f4_t xv = xrow[0];
  for (int k4 = 0; k4 < 16; ++k4) {
    f4_t xc = xv;
    if (k4 < 15) xv = xrow[k4 + 1];
    #pragma unroll
    for (int kk = 0; kk < 4; ++kk) {
      float xs = xc[kk];
      const f4_t* wr = (const f4_t*)&w1t[(k4 * 4 + kk) * 32];
      #pragma unroll
      for (int jq = 0; jq < 8; ++jq) acc[jq] += xs * wr[jq];
    }
  }
  #pragma unroll
  for (int jq = 0; jq < 8; ++jq) *(f4_t*)&hbuf[tid * 36 + jq * 4] = acc[jq];
  __syncthreads();
  if (tid < 32) {
    float s = 0.f, q = 0.f;
    for (int r = 0; r < 256; ++r) { float v = hbuf[r * 36 + tid]; s += v; q += v * v; }
    atomicAdd(&stats[t * 32 + tid], s);
    atomicAdd(&stats[96 + t * 32 + tid], q);
  }
}

// ---------------- BN layer-2 batch stats ----------------
__global__ __launch_bounds__(256) void k_stats2(
    const float* __restrict__ x, const float* __restrict__ W1, const float* __restrict__ W2,
    const float* __restrict__ g1, const float* __restrict__ be1, float* __restrict__ stats)
{
  __shared__ float w1t[64 * 32];
  __shared__ float w2t[32 * 32];
  __shared__ float sc1s[32], sh1s[32];
  __shared__ float hbuf[256 * 36];
  int tid = threadIdx.x;
  int t = blockIdx.x >> 7, chunk = blockIdx.x & 127;
  int row = chunk * 256 + tid;
  #pragma unroll
  for (int i = 0; i < 8; ++i) { int e = tid * 8 + i; w1t[(e & 63) * 32 + (e >> 6)] = W1[e]; }
  #pragma unroll
  for (int i = 0; i < 4; ++i) { int e = tid * 4 + i; w2t[(e & 31) * 32 + (e >> 5)] = W2[e]; }
  if (tid < 32) {
    float mean = stats[t * 32 + tid] * (1.f / NB);
    float var  = stats[96 + t * 32 + tid] * (1.f / NB) - mean * mean;
    float sc = g1[tid] * rsqrtf(var + 1e-5f);
    sc1s[tid] = sc; sh1s[tid] = be1[tid] - mean * sc;
  }
  __syncthreads();
  f4_t acc[8];
  #pragma unroll
  for (int jq = 0; jq < 8; ++jq) acc[jq] = (f4_t){0.f, 0.f, 0.f, 0.f};
  const f4_t* xrow = (const f4_t*)(x + ((size_t)t * NB + row) * 64);
  f4_t xv = xrow[0];
  for (int k4 = 0; k4 < 16; ++k4) {
    f4_t xc = xv;
    if (k4 < 15) xv = xrow[k4 + 1];
    #pragma unroll
    for (int kk = 0; kk < 4; ++kk) {
      float xs = xc[kk];
      const f4_t* wr = (const f4_t*)&w1t[(k4 * 4 + kk) * 32];
      #pragma unroll
      for (int jq = 0; jq < 8; ++jq) acc[jq] += xs * wr[jq];
    }
  }
  #pragma unroll
  for (int jq = 0; jq < 8; ++jq) {
    f4_t sc = *(const f4_t*)&sc1s[jq * 4];
    f4_t sh = *(const f4_t*)&sh1s[jq * 4];
    f4_t a = acc[jq] * sc + sh;
    #pragma unroll
    for (int c = 0; c < 4; ++c) a[c] = fmaxf(a[c], 0.f);
    *(f4_t*)&hbuf[tid * 36 + jq * 4] = a;
  }
  f4_t acc2[8];
  #pragma unroll
  for (int jq = 0; jq < 8; ++jq) acc2[jq] = (f4_t){0.f, 0.f, 0.f, 0.f};
  for (int k = 0; k < 32; ++k) {
    float a = hbuf[tid * 36 + k];
    const f4_t* wr = (const f4_t*)&w2t[k * 32];
    #pragma unroll
    for (int jq = 0; jq < 8; ++jq) acc2[jq] += a * wr[jq];
  }
  #pragma unroll
  for (int jq = 0; jq < 8; ++jq) *(f4_t*)&hbuf[tid * 36 + jq * 4] = acc2[jq];
  __syncthreads();
  if (tid < 32) {
    float s = 0.f, q = 0.f;
    for (int r = 0; r < 256; ++r) { float v = hbuf[r * 36 + tid]; s += v; q += v * v; }
    atomicAdd(&stats[192 + t * 32 + tid], s);
    atomicAdd(&stats[288 + t * 32 + tid], q);
  }
}

// ---------------- fused MLP encode + 28-step LSTM ----------------
__global__ __launch_bounds__(256, 2) void k_main(
    const float* __restrict__ x,
    const float* __restrict__ W1, const float* __restrict__ W2, const float* __restrict__ W3,
    const float* __restrict__ g1, const float* __restrict__ be1,
    const float* __restrict__ g2, const float* __restrict__ be2,
    const float* __restrict__ b3,
    const float* __restrict__ stats,
    const __bf16* __restrict__ Wcat, const __bf16* __restrict__ Wsum,
    const float* __restrict__ bsum,
    float* __restrict__ out)
{
  // LDS layout:
  // [0, 24576)      enc[3][64][64] bf16, XOR-swizzled rows
  // [24576, 40960)  h ping-pong [2][64][64] bf16, swizzled  (LSTM phase)
  // MLP-phase overlap (dead once LSTM starts):
  //   w1t @24576 (8KB), w2t @32768 (4KB), w3t @36864 (8KB),
  //   sc/sh @45056 (1.5KB), a_scr bf16 @46592 (13.5KB)
  __shared__ __align__(16) char smem[60416];
  float* w1t = (float*)(smem + 24576);
  float* w2t = (float*)(smem + 32768);
  float* w3t = (float*)(smem + 36864);
  float* sc1 = (float*)(smem + 45056);
  float* sh1 = sc1 + 96;
  float* sc2 = sc1 + 192;
  float* sh2 = sc1 + 288;
  __bf16* ascr = (__bf16*)(smem + 46592);

  const int tid = threadIdx.x;
  const int row0 = blockIdx.x * 64;

  #pragma unroll
  for (int i = 0; i < 8; ++i) { int e = tid * 8 + i; w1t[(e & 63) * 32 + (e >> 6)] = W1[e]; }
  #pragma unroll
  for (int i = 0; i < 4; ++i) { int e = tid * 4 + i; w2t[(e & 31) * 32 + (e >> 5)] = W2[e]; }
  #pragma unroll
  for (int i = 0; i < 8; ++i) { int e = tid * 8 + i; w3t[(e & 31) * 64 + (e >> 5)] = W3[e]; }
  if (tid < 96) {
    int t = tid >> 5, j = tid & 31;
    float mean = stats[t * 32 + j] * (1.f / NB);
    float var  = stats[96 + t * 32 + j] * (1.f / NB) - mean * mean;
    float sc = g1[j] * rsqrtf(var + 1e-5f);
    sc1[t * 32 + j] = sc; sh1[t * 32 + j] = be1[j] - mean * sc;
  } else if (tid < 192) {
    int t2 = (tid - 96) >> 5, j = tid & 31;
    float mean = stats[192 + t2 * 32 + j] * (1.f / NB);
    float var  = stats[288 + t2 * 32 + j] * (1.f / NB) - mean * mean;
    float sc = g2[j] * rsqrtf(var + 1e-5f);
    sc2[t2 * 32 + j] = sc; sh2[t2 * 32 + j] = be2[j] - mean * sc;
  }
  __syncthreads();

  if (tid < 192) {
    const int t = tid >> 6, r = tid & 63;
    const f4_t* xrow = (const f4_t*)(x + ((size_t)t * NB + row0 + r) * 64);
    f4_t acc[8];
    #pragma unroll
    for (int jq = 0; jq < 8; ++jq) acc[jq] = (f4_t){0.f, 0.f, 0.f, 0.f};
    f4_t xv = xrow[0];
    for (int k4 = 0; k4 < 16; ++k4) {
      f4_t xc = xv;
      if (k4 < 15) xv = xrow[k4 + 1];
      #pragma unroll
      for (int kk = 0; kk < 4; ++kk) {
        float xs = xc[kk];
        const f4_t* wr = (const f4_t*)&w1t[(k4 * 4 + kk) * 32];
        #pragma unroll
        for (int jq = 0; jq < 8; ++jq) acc[jq] += xs * wr[jq];
      }
    }
    __bf16* arow = ascr + tid * 36;
    #pragma unroll
    for (int jq = 0; jq < 8; ++jq) {
      f4_t sc = *(const f4_t*)&sc1[t * 32 + jq * 4];
      f4_t sh = *(const f4_t*)&sh1[t * 32 + jq * 4];
      f4_t a = acc[jq] * sc + sh;
      #pragma unroll
      for (int c = 0; c < 4; ++c) arow[jq * 4 + c] = (__bf16)fmaxf(a[c], 0.f);
    }
    f4_t acc2[8];
    #pragma unroll
    for (int jq = 0; jq < 8; ++jq) acc2[jq] = (f4_t){0.f, 0.f, 0.f, 0.f};
    for (int k = 0; k < 32; ++k) {
      float a = (float)arow[k];
      const f4_t* wr = (const f4_t*)&w2t[k * 32];
      #pragma unroll
      for (int jq = 0; jq < 8; ++jq) acc2[jq] += a * wr[jq];
    }
    #pragma unroll
    for (int jq = 0; jq < 8; ++jq) {
      f4_t sc = *(const f4_t*)&sc2[t * 32 + jq * 4];
      f4_t sh = *(const f4_t*)&sh2[t * 32 + jq * 4];
      f4_t a = acc2[jq] * sc + sh;
      #pragma unroll
      for (int c = 0; c < 4; ++c) arow[jq * 4 + c] = (__bf16)fmaxf(a[c], 0.f);
    }
    f4_t acc3[16];
    #pragma unroll
    for (int jq = 0; jq < 16; ++jq) acc3[jq] = (f4_t){0.f, 0.f, 0.f, 0.f};
    for (int k = 0; k < 32; ++k) {
      float a = (float)arow[k];
      const f4_t* wr = (const f4_t*)&w3t[k * 64];
      #pragma unroll
      for (int jq = 0; jq < 16; ++jq) acc3[jq] += a * wr[jq];
    }
    const f4_t* b3v = (const f4_t*)b3;
    char* encrow = smem + t * 8192 + r * 128;
    const int swz = (r & 7) << 4;
    #pragma unroll
    for (int c = 0; c < 8; ++c) {
      f4_t lo = acc3[2 * c]     + b3v[2 * c];
      f4_t hi = acc3[2 * c + 1] + b3v[2 * c + 1];
      bf8_t e8;
      e8[0] = (__bf16)lo[0]; e8[1] = (__bf16)lo[1]; e8[2] = (__bf16)lo[2]; e8[3] = (__bf16)lo[3];
      e8[4] = (__bf16)hi[0]; e8[5] = (__bf16)hi[1]; e8[6] = (__bf16)hi[2]; e8[7] = (__bf16)hi[3];
      *(bf8_t*)(encrow + ((c * 16) ^ swz)) = e8;
    }
  }
  __syncthreads();
  {
    u4_t z = (u4_t){0u, 0u, 0u, 0u};
    *(u4_t*)(smem + 24576 + tid * 16) = z;           // zero h[0]
    *(u4_t*)(smem + 24576 + 4096 + tid * 16) = z;
  }
  __syncthreads();

  // ---- LSTM: 3 cond steps + 25 pred steps ----
  const int wn = tid >> 6;
  const int l = tid & 63;
  const int l15 = l & 15, lh = l >> 4;
  const int hcol = wn * 16 + l15;

  bf8_t wcf[4][4];   // [gate][ktile] for K=128 (Z = [x|h]) steps
  bf8_t wsm[4][2];   // [gate][ktile] for K=64 (Wih+Whh) steps
  #pragma unroll
  for (int g = 0; g < 4; ++g) {
    int n = g * 64 + wn * 16 + l15;
    #pragma unroll
    for (int kt = 0; kt < 4; ++kt)
      wcf[g][kt] = *(const bf8_t*)(Wcat + n * 128 + kt * 32 + lh * 8);
    #pragma unroll
    for (int kt = 0; kt < 2; ++kt)
      wsm[g][kt] = *(const bf8_t*)(Wsum + n * 64 + kt * 32 + lh * 8);
  }
  f4_t bini[4];
  #pragma unroll
  for (int g = 0; g < 4; ++g) {
    float bv = bsum[g * 64 + wn * 16 + l15];
    bini[g] = (f4_t){bv, bv, bv, bv};
  }
  f4_t cst[4];
  #pragma unroll
  for (int mt = 0; mt < 4; ++mt) cst[mt] = (f4_t){0.f, 0.f, 0.f, 0.f};
  int obase[4][4];
  #pragma unroll
  for (int mt = 0; mt < 4; ++mt)
    #pragma unroll
    for (int rr = 0; rr < 4; ++rr)
      obase[mt][rr] = (row0 + mt * 16 + lh * 4 + rr) * 1600 + hcol;

  char* encb = smem;
  char* hb = smem + 24576;

  for (int s = 0; s < 28; ++s) {
    char* hcur = hb + (s & 1) * 8192;
    char* hnxt = hb + ((s + 1) & 1) * 8192;
    const char* xsrc = (s < 3) ? (encb + s * 8192)
                               : ((s == 3) ? (encb + 2 * 8192) : hcur);
    const bool full = (s < 4);
    #pragma unroll
    for (int mt = 0; mt < 4; ++mt) {
      const int rowb = mt * 16 + l15;
      const int swz = (rowb & 7) << 4;
      const int cb = lh * 16;
      const char* xr = xsrc + rowb * 128;
      f4_t gi = bini[0], gf = bini[1], gg = bini[2], go = bini[3];
      if (full) {
        const char* hr = hcur + rowb * 128;
        bf8_t av0 = *(const bf8_t*)(xr + (cb ^ swz));
        bf8_t av1 = *(const bf8_t*)(xr + ((64 + cb) ^ swz));
        bf8_t av2 = *(const bf8_t*)(hr + (cb ^ swz));
        bf8_t av3 = *(const bf8_t*)(hr + ((64 + cb) ^ swz));
        gi = MFMA16(av0, wcf[0][0], gi); gf = MFMA16(av0, wcf[1][0], gf);
        gg = MFMA16(av0, wcf[2][0], gg); go = MFMA16(av0, wcf[3][0], go);
        gi = MFMA16(av1, wcf[0][1], gi); gf = MFMA16(av1, wcf[1][1], gf);
        gg = MFMA16(av1, wcf[2][1], gg); go = MFMA16(av1, wcf[3][1], go);
        gi = MFMA16(av2, wcf[0][2], gi); gf = MFMA16(av2, wcf[1][2], gf);
        gg = MFMA16(av2, wcf[2][2], gg); go = MFMA16(av2, wcf[3][2], go);
        gi = MFMA16(av3, wcf[0][3], gi); gf = MFMA16(av3, wcf[1][3], gf);
        gg = MFMA16(av3, wcf[2][3], gg); go = MFMA16(av3, wcf[3][3], go);
      } else {
        bf8_t av0 = *(const bf8_t*)(xr + (cb ^ swz));
        bf8_t av1 = *(const bf8_t*)(xr + ((64 + cb) ^ swz));
        gi = MFMA16(av0, wsm[0][0], gi); gf = MFMA16(av0, wsm[1][0], gf);
        gg = MFMA16(av0, wsm[2][0], gg); go = MFMA16(av0, wsm[3][0], go);
        gi = MFMA16(av1, wsm[0][1], gi); gf = MFMA16(av1, wsm[1][1], gf);
        gg = MFMA16(av1, wsm[2][1], gg); go = MFMA16(av1, wsm[3][1], go);
      }
      #pragma unroll
      for (int rr = 0; rr < 4; ++rr) {
        float iv = sigf(gi[rr]);
        float fv = sigf(gf[rr]);
        float gv = tanhf_(gg[rr]);
        float ov = sigf(go[rr]);
        float cN = fv * cst[mt][rr] + iv * gv;
        cst[mt][rr] = cN;
        float hv = ov * tanhf_(cN);
        const int hrow = mt * 16 + lh * 4 + rr;
        *(__bf16*)(hnxt + hrow * 128 + ((hcol * 2) ^ ((hrow & 7) << 4))) = (__bf16)hv;
        if (s >= 3) out[obase[mt][rr] + (s - 3) * 64] = hv;
      }
    }
    __syncthreads();
  }
}

extern "C" void kernel_launch(void* const* d_in, const int* in_sizes, int n_in,
                              void* d_out, int out_size, void* d_ws, size_t ws_size,
                              hipStream_t stream) {
  const float* x   = (const float*)d_in[0];
  const float* W1  = (const float*)d_in[1];
  // d_in[2] = b1 (cancels in BN), d_in[6] = b2 (cancels in BN)
  const float* g1  = (const float*)d_in[3];
  const float* be1 = (const float*)d_in[4];
  const float* W2  = (const float*)d_in[5];
  const float* g2  = (const float*)d_in[7];
  const float* be2 = (const float*)d_in[8];
  const float* W3  = (const float*)d_in[9];
  const float* b3  = (const float*)d_in[10];
  const float* Wih = (const float*)d_in[11];
  const float* Whh = (const float*)d_in[12];
  const float* bih = (const float*)d_in[13];
  const float* bhh = (const float*)d_in[14];
  float* out = (float*)d_out;

  char* ws = (char*)d_ws;
  float*  stats = (float*)ws;                       // [384] f32: sum1,sq1,sum2,sq2
  float*  bsum  = (float*)(ws + 2048);              // [256]
  __bf16* Wcat  = (__bf16*)(ws + 4096);             // [256][128]
  __bf16* Wsum  = (__bf16*)(ws + 4096 + 65536);     // [256][64]

  hipMemsetAsync(stats, 0, 1536, stream);
  k_prep<<<64, 256, 0, stream>>>(Wih, Whh, bih, bhh, Wcat, Wsum, bsum);
  k_stats1<<<384, 256, 0, stream>>>(x, W1, stats);
  k_stats2<<<384, 256, 0, stream>>>(x, W1, W2, g1, be1, stats);
  k_main<<<512, 256, 0, stream>>>(x, W1, W2, W3, g1, be1, g2, be2, b3,
                                  stats, Wcat, Wsum, bsum, out);
}